// Round 7
// baseline (244.954 us; speedup 1.0000x reference)
//
#include <hip/hip_runtime.h>

#define DEVINL __device__ __forceinline__

constexpr int BB = 256;   // batch
constexpr int TT = 512;   // time steps
constexpr int FF = 128;   // features
constexpr int HH = 128;   // hidden size

typedef float f2 __attribute__((ext_vector_type(2)));

DEVINL f2 pkfma(f2 a, f2 b, f2 c) { return __builtin_elementwise_fma(a, b, c); }
DEVINL f2 splat(float s) { return (f2){s, s}; }

// ---- DPP cross-lane helpers (all-lanes-active call sites only) ----
template<int CTRL>
DEVINL float dppf(float x) {
  return __builtin_bit_cast(float,
    __builtin_amdgcn_update_dpp(0, __builtin_bit_cast(int, x), CTRL, 0xF, 0xF, true));
}

// allreduce within each 16-lane row (values end uniform per row)
DEVINL float red16(float v) {
  v += dppf<0xB1>(v);    // quad_perm [1,0,3,2]  == xor 1
  v += dppf<0x4E>(v);    // quad_perm [2,3,0,1]  == xor 2
  v += dppf<0x141>(v);   // row_half_mirror      (== xor 4 here)
  v += dppf<0x140>(v);   // row_mirror           (== xor 8 here)
  return v;
}

// cross-row sums via gfx950 permlane swaps (VALU, no DS / lgkmcnt).
DEVINL float swap16add(float v) {
  float b = v;
  asm("s_nop 0\n\tv_permlane16_swap_b32 %0, %1" : "+v"(v), "+v"(b));
  return v + b;
}
DEVINL float swap32add(float v) {
  float b = v;
  asm("s_nop 0\n\tv_permlane32_swap_b32 %0, %1" : "+v"(v), "+v"(b));
  return v + b;
}
DEVINL float red64(float v)  { return swap32add(swap16add(red16(v))); }

DEVINL float rcp_f(float x){ return __builtin_amdgcn_rcpf(x); }
DEVINL float rsq_f(float x){ return __builtin_amdgcn_rsqf(x); }
DEVINL float ex2_f(float x){ return __builtin_amdgcn_exp2f(x); }
DEVINL f2 ex2_2(f2 v){ return (f2){ ex2_f(v.x), ex2_f(v.y) }; }

// ============================================================
// Kernel 1: y_x[r][q] = sum_f x[r][f] * Win_w[q][128+f] + Win_b[q]
// ============================================================
__global__ __launch_bounds__(64)
void yx_pre(const float* __restrict__ x,
            const float* __restrict__ Win_w,
            const float* __restrict__ Win_b,
            float* __restrict__ yx, int rowsPerBlk)
{
  const int lane = threadIdx.x;
  const float wx0a = Win_w[0*256 + 128 + 2*lane], wx0b = Win_w[0*256 + 129 + 2*lane];
  const float wx1a = Win_w[1*256 + 128 + 2*lane], wx1b = Win_w[1*256 + 129 + 2*lane];
  const float wx2a = Win_w[2*256 + 128 + 2*lane], wx2b = Win_w[2*256 + 129 + 2*lane];
  const float wx3a = Win_w[3*256 + 128 + 2*lane], wx3b = Win_w[3*256 + 129 + 2*lane];
  const float bb0 = Win_b[0], bb1 = Win_b[1], bb2 = Win_b[2], bb3 = Win_b[3];

  const int r0 = blockIdx.x * rowsPerBlk;
  float2 xv = *reinterpret_cast<const float2*>(x + (size_t)r0 * FF + 2*lane);
  for (int k = 0; k < rowsPerBlk; ++k) {
    const int r = r0 + k;
    float2 cur = xv;
    if (k + 1 < rowsPerBlk)
      xv = *reinterpret_cast<const float2*>(x + (size_t)(r + 1) * FF + 2*lane);
    float p0 = fmaf(cur.x, wx0a, cur.y * wx0b);
    float p1 = fmaf(cur.x, wx1a, cur.y * wx1b);
    float p2 = fmaf(cur.x, wx2a, cur.y * wx2b);
    float p3 = fmaf(cur.x, wx3a, cur.y * wx3b);
    p0 = red64(p0); p1 = red64(p1); p2 = red64(p2); p3 = red64(p3);
    if (lane == 0)
      reinterpret_cast<float4*>(yx)[r] = make_float4(p0 + bb0, p1 + bb1, p2 + bb2, p3 + bb3);
  }
}

// ============================================================
// Kernel 2: recurrent scan — ONE chain per wave, 2 units/lane.
// yx staged in LDS (zero VMEM loads in loop, lgkm-only); h stores
// batched 8 steps into alternating register banks (vmcnt stream is
// stores-only with >=16-step register reuse distance).
// Chain-shortened math: d = r*(cw*y + sw*rr); tree-z; scaled
// c~ = T2E*c; early o = rcp(1+d); h = (v-1)*o*rcp(v+1).
// ============================================================
__global__ __launch_bounds__(64)
void qlstm_rec(const float* __restrict__ Win_w,
               const float* __restrict__ Wout_w,
               const float* __restrict__ Wout_b,
               const float* __restrict__ w_f,
               const float* __restrict__ w_i,
               const float* __restrict__ w_u,
               const float* __restrict__ w_o,
               const float* __restrict__ yx,
               float* __restrict__ out)
{
  __shared__ float4 yls[TT];   // 8 KB: this chain's y_x sequence

  const int lane = threadIdx.x;
  const int b    = blockIdx.x;
  const int j0   = 2*lane, j1 = 2*lane + 1;

  constexpr float L2E  = 1.4426950408889634f;
  constexpr float NL2E = -L2E;           // sigmoid prescale (f,i,o)
  constexpr float T2E  = 2.0f * L2E;     // tanh prescale (u, tanh(c))
  constexpr float IT2E = 0.34657359027997264f;  // 1/T2E

  // ---- stage yx chain into LDS (coalesced, once) ----
  {
    const float4* src = reinterpret_cast<const float4*>(yx) + (size_t)b * TT;
    #pragma unroll
    for (int k = 0; k < 8; ++k)
      yls[k*64 + lane] = src[k*64 + lane];
  }
  __syncthreads();

  // recurrent weights Wh[q][j0], Wh[q][j1]
  float whA[4], whB[4];
  #pragma unroll
  for (int q = 0; q < 4; ++q) {
    whA[q] = Win_w[q*256 + j0];
    whB[q] = Win_w[q*256 + j1];
  }

  // z weight packs per unit: fi-pair = {NL2E, NL2E}; uo-pair = {T2E, NL2E}
  const float4 r0v = reinterpret_cast<const float4*>(Wout_w)[j0];
  const float4 r1v = reinterpret_cast<const float4*>(Wout_w)[j1];
  const float w0[4] = {r0v.x, r0v.y, r0v.z, r0v.w};
  const float w1[4] = {r1v.x, r1v.y, r1v.z, r1v.w};
  f2 wfi0[4], wfi1[4], wuo0[4], wuo1[4];
  #pragma unroll
  for (int k = 0; k < 4; ++k) {
    wfi0[k] = (f2){ w0[k]*NL2E, w0[k]*NL2E };
    wfi1[k] = (f2){ w1[k]*NL2E, w1[k]*NL2E };
    wuo0[k] = (f2){ w0[k]*T2E,  w0[k]*NL2E };
    wuo1[k] = (f2){ w1[k]*T2E,  w1[k]*NL2E };
  }
  const float b0s = Wout_b[j0], b1s = Wout_b[j1];
  const f2 bfi0 = (f2){ b0s*NL2E, b0s*NL2E };
  const f2 bfi1 = (f2){ b1s*NL2E, b1s*NL2E };
  const f2 buo0 = (f2){ b0s*T2E,  b0s*NL2E };
  const f2 buo1 = (f2){ b1s*T2E,  b1s*NL2E };

  // ring RY coefficients packed across gate pairs (f,i) and (u,o)
  f2 cwfi[4], swfi[4], cwuo[4], swuo[4];
  #pragma unroll
  for (int q = 0; q < 4; ++q) {
    cwfi[q] = (f2){ -cosf(w_f[q]), -cosf(w_i[q]) };
    swfi[q] = (f2){ -sinf(w_f[q]), -sinf(w_i[q]) };
    cwuo[q] = (f2){ -cosf(w_u[q]), -cosf(w_o[q]) };
    swuo[q] = (f2){ -sinf(w_u[q]), -sinf(w_o[q]) };
  }

  float h0 = 0.f, h1 = 0.f;
  float ct0 = 0.f, ct1 = 0.f;            // c~ = T2E * c

  float* outp = out + (size_t)b * TT * HH + j0;

  float4 ycur = yls[0];
  int tt = 0;

  float2 hbA[8], hbB[8];

  // one step: consumes yc, produces h0,h1 (and updates ct0,ct1)
  auto STEP = [&](const float4 yc) {
    // ---- y = Wh @ h + y_x (DPP + permlane 64-lane allreduce) ----
    float s0 = fmaf(h0, whA[0], h1 * whB[0]);
    float s1 = fmaf(h0, whA[1], h1 * whB[1]);
    float s2 = fmaf(h0, whA[2], h1 * whB[2]);
    float s3 = fmaf(h0, whA[3], h1 * whB[3]);
    s0 = red64(s0); s1 = red64(s1); s2 = red64(s2); s3 = red64(s3);

    const f2 y01 = (f2){ s0 + yc.x, s1 + yc.y };
    const f2 y23 = (f2){ s2 + yc.z, s3 + yc.w };

    // ---- r = rsq(1+y^2), rr = rsq(1+y^4) per qubit ----
    const f2 y2a = y01 * y01, y2b = y23 * y23;
    const f2 p1a = y2a + 1.f, p1b = y2b + 1.f;
    const f2 p2a = pkfma(y2a, y2a, splat(1.f));
    const f2 p2b = pkfma(y2b, y2b, splat(1.f));
    const f2 rA  = (f2){ rsq_f(p1a.x), rsq_f(p1a.y) };
    const f2 rB  = (f2){ rsq_f(p1b.x), rsq_f(p1b.y) };
    const f2 rrA = (f2){ rsq_f(p2a.x), rsq_f(p2a.y) };
    const f2 rrB = (f2){ rsq_f(p2b.x), rsq_f(p2b.y) };

    // ---- d_q = r*(cw*y + sw*rr), packed across gate pairs ----
    const f2 d0fi = pkfma(cwfi[0], splat(y01.x), swfi[0] * splat(rrA.x)) * splat(rA.x);
    const f2 d1fi = pkfma(cwfi[1], splat(y01.y), swfi[1] * splat(rrA.y)) * splat(rA.y);
    const f2 d2fi = pkfma(cwfi[2], splat(y23.x), swfi[2] * splat(rrB.x)) * splat(rB.x);
    const f2 d3fi = pkfma(cwfi[3], splat(y23.y), swfi[3] * splat(rrB.y)) * splat(rB.y);
    const f2 d0uo = pkfma(cwuo[0], splat(y01.x), swuo[0] * splat(rrA.x)) * splat(rA.x);
    const f2 d1uo = pkfma(cwuo[1], splat(y01.y), swuo[1] * splat(rrA.y)) * splat(rA.y);
    const f2 d2uo = pkfma(cwuo[2], splat(y23.x), swuo[2] * splat(rrB.x)) * splat(rB.x);
    const f2 d3uo = pkfma(cwuo[3], splat(y23.y), swuo[3] * splat(rrB.y)) * splat(rB.y);

    // ---- ring-permuted expvals ----
    const f2 e1fi = d0fi * d1fi, dpfi = d2fi * d3fi;
    const f2 e0fi = d1fi * dpfi, e2fi = e1fi * d2fi, e3fi = e1fi * dpfi;
    const f2 e1uo = d0uo * d1uo, dpuo = d2uo * d3uo;
    const f2 e0uo = d1uo * dpuo, e2uo = e1uo * d2uo, e3uo = e1uo * dpuo;

    // ---- z packs (tree form, depth 3) ----
    const f2 zfi0 = pkfma(e0fi, wfi0[0], e1fi * wfi0[1])
                  + pkfma(e2fi, wfi0[2], pkfma(e3fi, wfi0[3], bfi0));
    const f2 zfi1 = pkfma(e0fi, wfi1[0], e1fi * wfi1[1])
                  + pkfma(e2fi, wfi1[2], pkfma(e3fi, wfi1[3], bfi1));
    const f2 zuo0 = pkfma(e0uo, wuo0[0], e1uo * wuo0[1])
                  + pkfma(e2uo, wuo0[2], pkfma(e3uo, wuo0[3], buo0));
    const f2 zuo1 = pkfma(e0uo, wuo1[0], e1uo * wuo1[1])
                  + pkfma(e2uo, wuo1[2], pkfma(e3uo, wuo1[3], buo1));

    // ---- activations: exfi = {a,b}, exuo = {u,d} ----
    const f2 exfi0 = ex2_2(zfi0), exfi1 = ex2_2(zfi1);
    const f2 exuo0 = ex2_2(zuo0), exuo1 = ex2_2(zuo1);
    const f2 pfi0 = exfi0 + 1.f, pfi1 = exfi1 + 1.f;   // {1+a, 1+b}
    const f2 puo0 = exuo0 + 1.f, puo1 = exuo1 + 1.f;   // {1+u, 1+d}
    const float um0 = fmaf(T2E, exuo0.x, -T2E);        // T2E*(u-1)
    const float um1 = fmaf(T2E, exuo1.x, -T2E);
    const float o0  = rcp_f(puo0.y);                   // output gate (off-chain)
    const float o1  = rcp_f(puo1.y);

    // ---- scaled c update: c~' = (c~*t1 + (1+a)*um) * rcp((1+a)*t1) ----
    {
      const float t1 = pfi0.y * puo0.x;
      const float num = fmaf(ct0, t1, pfi0.x * um0);
      ct0 = num * rcp_f(pfi0.x * t1);
    }
    {
      const float t1 = pfi1.y * puo1.x;
      const float num = fmaf(ct1, t1, pfi1.x * um1);
      ct1 = num * rcp_f(pfi1.x * t1);
    }

    // ---- h = (V-1)*o*rcp(V+1), V = exp2(c~) ----
    {
      const float V = ex2_f(ct0);
      h0 = ((V - 1.f) * o0) * rcp_f(V + 1.f);
    }
    {
      const float V = ex2_f(ct1);
      h1 = ((V - 1.f) * o1) * rcp_f(V + 1.f);
    }
  };

  for (int it = 0; it < TT / 16; ++it) {
    // ---- group A: 8 steps into hbA ----
    #pragma unroll
    for (int s = 0; s < 8; ++s) {
      const int tn = (tt + 1 < TT) ? tt + 1 : TT - 1;
      const float4 ynext = yls[tn];
      STEP(ycur);
      hbA[s] = make_float2(h0, h1);
      ycur = ynext; ++tt;
    }
    #pragma unroll
    for (int s = 0; s < 8; ++s)
      *reinterpret_cast<float2*>(outp + s*HH) = hbA[s];
    outp += 8*HH;

    // ---- group B: 8 steps into hbB ----
    #pragma unroll
    for (int s = 0; s < 8; ++s) {
      const int tn = (tt + 1 < TT) ? tt + 1 : TT - 1;
      const float4 ynext = yls[tn];
      STEP(ycur);
      hbB[s] = make_float2(h0, h1);
      ycur = ynext; ++tt;
    }
    #pragma unroll
    for (int s = 0; s < 8; ++s)
      *reinterpret_cast<float2*>(outp + s*HH) = hbB[s];
    outp += 8*HH;
  }

  const size_t hoff = (size_t)BB * TT * HH;
  *reinterpret_cast<float2*>(out + hoff + (size_t)b * HH + j0) = make_float2(h0, h1);
  const size_t coff = hoff + (size_t)BB * HH;
  *reinterpret_cast<float2*>(out + coff + (size_t)b * HH + j0) =
      make_float2(ct0 * IT2E, ct1 * IT2E);
}

extern "C" void kernel_launch(void* const* d_in, const int* in_sizes, int n_in,
                              void* d_out, int out_size, void* d_ws, size_t ws_size,
                              hipStream_t stream) {
  const float* x      = (const float*)d_in[0];
  const float* Win_w  = (const float*)d_in[1];
  const float* Win_b  = (const float*)d_in[2];
  const float* Wout_w = (const float*)d_in[3];
  const float* Wout_b = (const float*)d_in[4];
  const float* w_f    = (const float*)d_in[5];
  const float* w_i    = (const float*)d_in[6];
  const float* w_u    = (const float*)d_in[7];
  const float* w_o    = (const float*)d_in[8];
  float* out = (float*)d_out;
  float* yx  = (float*)d_ws;   // B*T*4 floats = 2 MB scratch

  const int rows = BB * TT;          // 131072
  const int rowsPerBlk = 16;
  yx_pre<<<rows / rowsPerBlk, 64, 0, stream>>>(x, Win_w, Win_b, yx, rowsPerBlk);
  qlstm_rec<<<BB, 64, 0, stream>>>(Win_w, Wout_w, Wout_b, w_f, w_i, w_u, w_o, yx, out);
}